// Round 4
// baseline (435.254 us; speedup 1.0000x reference)
//
#include <hip/hip_runtime.h>

// KerasCustomMappingLayer: B=32768 rows x H=512 sequential steps, out (B,H,6) f32.
//
// R4: ZERO-REPLAY chunking. The carry (px,py) is reset whenever l[k] > 192
// (k-only condition, identical for all rows). Chunk c's start is snapped to
// the last reset <= 32*c, so every chunk starts at a reset (carry-in dead,
// px=py=0) or at 0 (start_pos). No replay reads, no replay compute.
// Ragged first/last frames use a guarded path; steady frames use the proven
// 16-step register-staged F4 loads (64B/lane/array, full-line consumption).
// Plain stores only (nontemporal caused 2.6x write amplification in R2).
// Numerics: exact numpy fp32 graph (contract off, IEEE div/sqrt) so the
// wall-indicator comparisons never flip vs the reference.

#define H 512
#define NCH 16
#define CHUNK 32   // nominal chunk length (boundaries snap to resets)
#define GRP 16     // steps per register frame

typedef float v4f __attribute__((ext_vector_type(4)));
struct alignas(16) F4 { float v[4]; };

__device__ __forceinline__ void step_core(
    float m0, float m1, float m2, float m3,
    float lk, float isslf, float slnk, float scosk, float ssink,
    bool nfse, float& px, float& py, float* o /* 6 floats or nullptr */)
{
#pragma clang fp contract(off)
    // wall constants: match numpy's f64-scalar -> f32 cast
    const float WL = (float)(0.05 * 512.0);
    const float WR = (float)(0.95 * 512.0);
    const float WT = (float)(0.05 * 384.0);
    const float WB = (float)(0.95 * 384.0);

    // normalization (cos_list/sin_list): len = sqrt(c*c + s*s); c/len, s/len
    float q0 = __fmul_rn(m0, m0);
    float q2 = __fmul_rn(m2, m2);
    float len1 = __fsqrt_rn(__fadd_rn(q0, q2));
    float ck = __fdiv_rn(m0, len1);
    float sk = __fdiv_rn(m2, len1);
    float q1 = __fmul_rn(m1, m1);
    float q3 = __fmul_rn(m3, m3);
    float len2 = __fsqrt_rn(__fadd_rn(q1, q3));
    float ck2 = __fdiv_rn(m1, len2);
    float sk2 = __fdiv_rn(m3, len2);

    bool rr = lk > 192.0f;                 // l > Y_MAX/2  (the carry reset)
    float half_l = __fmul_rn(lk, 0.5f);
    float wl = __fadd_rn(WL, half_l);
    float wr = __fadd_rn(WR, -half_l);
    float wt = __fadd_rn(WT, half_l);
    float wb = __fadd_rn(WB, -half_l);

    float dx = __fmul_rn(lk, ck);
    float dy = __fmul_rn(lk, sk);
    float adx = fabsf(dx);
    float ady = fabsf(dy);

    // x_delta = |dx|*w_l - |dx|*w_r + dx*w_xm  (exactly one/none region active)
    float xd = (px < wl) ? adx : ((px > wr) ? -adx : (((px > wl) && (px < wr)) ? dx : 0.0f));
    float yd = (py < wt) ? ady : ((py > wb) ? -ady : (((py > wt) && (py < wb)) ? dy : 0.0f));

    float rx = __fadd_rn(256.0f, __fmul_rn(256.0f, m0));  // rerand_x
    float ry = __fadd_rn(192.0f, __fmul_rn(192.0f, m2));  // rerand_y

    float _x = rr ? rx : __fadd_rn(px, xd);
    float _y = rr ? ry : __fadd_rn(py, yd);

    bool issl = isslf != 0.0f;
    float e1 = __fmul_rn(ck2, slnk);
    float e2 = __fmul_rn(sk2, slnk);
    float ex = __fadd_rn(_x, e1);   // _x + ck2*slider_len
    float ey = __fadd_rn(_y, e2);

    if (o) {
        float o0 = __fdiv_rn(_x, 512.0f);
        float o1 = __fdiv_rn(_y, 384.0f);
        o[0] = o0;
        o[1] = o1;
        if (issl) {
            float t1 = __fmul_rn(ck2, scosk);
            float t2 = __fmul_rn(sk2, ssink);
            o[2] = __fadd_rn(t1, -t2);      // _oa
            float t3 = __fmul_rn(ck2, ssink);
            float t4 = __fmul_rn(sk2, scosk);
            o[3] = __fadd_rn(t3, t4);       // _ob
            o[4] = __fdiv_rn(ex, 512.0f);
            o[5] = __fdiv_rn(ey, 384.0f);
        } else {
            o[2] = rr ? ck2 : ck;           // _a = rr*ck2 + nrr*ck
            o[3] = rr ? sk2 : sk;           // _b
            o[4] = o0;
            o[5] = o1;
        }
    }

    if (issl) {
        px = nfse ? ex : _x;
        py = nfse ? ey : _y;
    } else {
        px = _x;
        py = _y;
    }
}

__global__ __launch_bounds__(256, 4)
void construct_map_kernel(const float* __restrict__ mapvars,
                          const float* __restrict__ rel,
                          const float* __restrict__ start_pos,
                          const float* __restrict__ lmul,
                          const int* __restrict__ nfse_p,
                          float* __restrict__ out)
{
    __shared__ float s_issl[H];
    __shared__ float s_slen[H];
    __shared__ float s_scos[H];
    __shared__ float s_ssin[H];
    __shared__ float s_lk[H];

    float lm = lmul[0];
    for (int i = threadIdx.x; i < H; i += blockDim.x) {
        s_issl[i] = rel[i];             // rel[0]: is_slider
        s_slen[i] = rel[H + i];         // rel[1]: slider_lengths
        s_scos[i] = rel[3 * H + i];     // rel[3]: slider cos
        s_ssin[i] = rel[4 * H + i];     // rel[4]: slider sin
        s_lk[i]   = __fmul_rn(lm, rel[5 * H + i]);  // l = lm * note_dist
    }
    __syncthreads();

    const int row = blockIdx.x * blockDim.x + threadIdx.x;
    const int c = blockIdx.y;                          // chunk id (block-uniform)
    const bool nfse = (nfse_p[0] != 0);

    // ---- reset-snapped boundaries: chunk covers [a, bnd) ----
    int a = 0;
    if (c > 0) {
        for (int t = c * CHUNK - 1; t > 0; --t)
            if (s_lk[t] > 192.0f) { a = t; break; }
    }
    int bnd = H;
    if (c < NCH - 1) {
        bnd = 0;
        for (int t = (c + 1) * CHUNK - 1; t > 0; --t)
            if (s_lk[t] > 192.0f) { bnd = t; break; }
    }
    if (a >= bnd) return;                              // empty chunk

    float px, py;
    if (a == 0) { px = start_pos[0]; py = start_pos[1]; }
    else        { px = 0.0f;         py = 0.0f; }      // a is a reset: carry dead

    const int a4 = a & ~3;                             // 4-aligned run start
    const float* rp = mapvars + (size_t)row * (4 * H);
    float* orow = out + (size_t)row * (H * 6);

    for (int f = a & ~(GRP - 1); f < bnd; f += GRP) {
        if (f >= a && f + GRP <= bnd) {
            // ---- fast path: full 16-step frame (64B/lane/array) ----
            F4 A[4][GRP / 4];
#pragma unroll
            for (int ar = 0; ar < 4; ++ar)
#pragma unroll
                for (int t = 0; t < GRP / 4; ++t)
                    A[ar][t] = *(const F4*)(rp + ar * H + f + 4 * t);

#pragma unroll
            for (int t = 0; t < GRP / 4; ++t) {
                float o[24];
#pragma unroll
                for (int j = 0; j < 4; ++j) {
                    const int k = f + 4 * t + j;
                    step_core(A[0][t].v[j], A[1][t].v[j], A[2][t].v[j], A[3][t].v[j],
                              s_lk[k], s_issl[k], s_slen[k], s_scos[k], s_ssin[k],
                              nfse, px, py, o + 6 * j);
                }
                float* ow = orow + (size_t)(f + 4 * t) * 6;
#pragma unroll
                for (int q = 0; q < 6; ++q) {
                    v4f v;
                    v.x = o[q * 4 + 0];
                    v.y = o[q * 4 + 1];
                    v.z = o[q * 4 + 2];
                    v.w = o[q * 4 + 3];
                    *(v4f*)(ow + 4 * q) = v;   // plain store: L2 write-combines
                }
            }
        } else {
            // ---- guarded path: ragged first/last frame (block-uniform guards) ----
            F4 A[4][GRP / 4];
#pragma unroll
            for (int t = 0; t < GRP / 4; ++t) {
                const int k4 = f + 4 * t;
                if (k4 >= a4 && k4 < bnd) {
#pragma unroll
                    for (int ar = 0; ar < 4; ++ar)
                        A[ar][t] = *(const F4*)(rp + ar * H + k4);
                }
            }
#pragma unroll
            for (int t = 0; t < GRP / 4; ++t) {
#pragma unroll
                for (int j = 0; j < 4; ++j) {
                    const int k = f + 4 * t + j;
                    if (k >= a4 && k < bnd) {
                        float o[6];
                        const bool emit = (k >= a);
                        step_core(A[0][t].v[j], A[1][t].v[j], A[2][t].v[j], A[3][t].v[j],
                                  s_lk[k], s_issl[k], s_slen[k], s_scos[k], s_ssin[k],
                                  nfse, px, py, emit ? o : (float*)nullptr);
                        if (emit) {
                            float* ow = orow + (size_t)k * 6;
#pragma unroll
                            for (int q = 0; q < 6; ++q) ow[q] = o[q];
                        }
                    }
                }
            }
        }
    }
}

extern "C" void kernel_launch(void* const* d_in, const int* in_sizes, int n_in,
                              void* d_out, int out_size, void* d_ws, size_t ws_size,
                              hipStream_t stream) {
    const float* mapvars = (const float*)d_in[0];
    const float* rel     = (const float*)d_in[1];
    const float* sp      = (const float*)d_in[2];
    const float* lm      = (const float*)d_in[3];
    const int*   nfse    = (const int*)d_in[4];
    float* out = (float*)d_out;

    const int B = in_sizes[0] / (4 * H);   // 32768
    dim3 grid(B / 256, NCH);
    hipLaunchKernelGGL(construct_map_kernel, grid, dim3(256), 0, stream,
                       mapvars, rel, sp, lm, nfse, out);
}

// Round 5
// 376.563 us; speedup vs baseline: 1.1559x; 1.1559x over previous
//
#include <hip/hip_runtime.h>

// KerasCustomMappingLayer: B=32768 rows x H=512 sequential steps, out (B,H,6) f32.
//
// R5 = R3 structure (all-full-frame loads/stores; replay from last reset) with:
//  (a) F4-vectorized replay loads (R3's scalar replay fetched 4 lines/step ->
//      ~520MB waste; aligned F4 groups cut that ~4x),
//  (b) __launch_bounds__(256,8): R3/R4 were capped at 50% occupancy (16 waves/CU)
//      and latency-bound (BW 3.66 TB/s, VALUBusy 19%). 2048 blocks = 8/CU.
// Stores stay plain f32x4 full-frame (R1/R3 proved exactly-minimal WRITE;
// nontemporal (R2) and ragged scalar stores (R4) both amplified writes ~2x).
// Numerics: exact numpy fp32 graph (contract off, IEEE div/sqrt) so the
// wall-indicator comparisons never flip vs the reference.

#define H 512
#define NCH 16
#define CHUNK 32   // H / NCH
#define GRP 16     // steps per register frame

typedef float v4f __attribute__((ext_vector_type(4)));
struct alignas(16) F4 { float v[4]; };

__device__ __forceinline__ void step_core(
    float m0, float m1, float m2, float m3,
    float lk, float isslf, float slnk, float scosk, float ssink,
    bool nfse, float& px, float& py, float* o /* 6 floats or nullptr */)
{
#pragma clang fp contract(off)
    // wall constants: match numpy's f64-scalar -> f32 cast
    const float WL = (float)(0.05 * 512.0);
    const float WR = (float)(0.95 * 512.0);
    const float WT = (float)(0.05 * 384.0);
    const float WB = (float)(0.95 * 384.0);

    // normalization (cos_list/sin_list): len = sqrt(c*c + s*s); c/len, s/len
    float q0 = __fmul_rn(m0, m0);
    float q2 = __fmul_rn(m2, m2);
    float len1 = __fsqrt_rn(__fadd_rn(q0, q2));
    float ck = __fdiv_rn(m0, len1);
    float sk = __fdiv_rn(m2, len1);
    float q1 = __fmul_rn(m1, m1);
    float q3 = __fmul_rn(m3, m3);
    float len2 = __fsqrt_rn(__fadd_rn(q1, q3));
    float ck2 = __fdiv_rn(m1, len2);
    float sk2 = __fdiv_rn(m3, len2);

    bool rr = lk > 192.0f;                 // l > Y_MAX/2  (the carry reset)
    float half_l = __fmul_rn(lk, 0.5f);
    float wl = __fadd_rn(WL, half_l);
    float wr = __fadd_rn(WR, -half_l);
    float wt = __fadd_rn(WT, half_l);
    float wb = __fadd_rn(WB, -half_l);

    float dx = __fmul_rn(lk, ck);
    float dy = __fmul_rn(lk, sk);
    float adx = fabsf(dx);
    float ady = fabsf(dy);

    // x_delta = |dx|*w_l - |dx|*w_r + dx*w_xm  (exactly one/none region active)
    float xd = (px < wl) ? adx : ((px > wr) ? -adx : (((px > wl) && (px < wr)) ? dx : 0.0f));
    float yd = (py < wt) ? ady : ((py > wb) ? -ady : (((py > wt) && (py < wb)) ? dy : 0.0f));

    float rx = __fadd_rn(256.0f, __fmul_rn(256.0f, m0));  // rerand_x
    float ry = __fadd_rn(192.0f, __fmul_rn(192.0f, m2));  // rerand_y

    float _x = rr ? rx : __fadd_rn(px, xd);
    float _y = rr ? ry : __fadd_rn(py, yd);

    bool issl = isslf != 0.0f;
    float e1 = __fmul_rn(ck2, slnk);
    float e2 = __fmul_rn(sk2, slnk);
    float ex = __fadd_rn(_x, e1);   // _x + ck2*slider_len
    float ey = __fadd_rn(_y, e2);

    if (o) {
        float o0 = __fdiv_rn(_x, 512.0f);
        float o1 = __fdiv_rn(_y, 384.0f);
        o[0] = o0;
        o[1] = o1;
        if (issl) {
            float t1 = __fmul_rn(ck2, scosk);
            float t2 = __fmul_rn(sk2, ssink);
            o[2] = __fadd_rn(t1, -t2);      // _oa
            float t3 = __fmul_rn(ck2, ssink);
            float t4 = __fmul_rn(sk2, scosk);
            o[3] = __fadd_rn(t3, t4);       // _ob
            o[4] = __fdiv_rn(ex, 512.0f);
            o[5] = __fdiv_rn(ey, 384.0f);
        } else {
            o[2] = rr ? ck2 : ck;           // _a = rr*ck2 + nrr*ck
            o[3] = rr ? sk2 : sk;           // _b
            o[4] = o0;
            o[5] = o1;
        }
    }

    if (issl) {
        px = nfse ? ex : _x;
        py = nfse ? ey : _y;
    } else {
        px = _x;
        py = _y;
    }
}

__global__ __launch_bounds__(256, 8)
void construct_map_kernel(const float* __restrict__ mapvars,
                          const float* __restrict__ rel,
                          const float* __restrict__ start_pos,
                          const float* __restrict__ lmul,
                          const int* __restrict__ nfse_p,
                          float* __restrict__ out)
{
    __shared__ float s_issl[H];
    __shared__ float s_slen[H];
    __shared__ float s_scos[H];
    __shared__ float s_ssin[H];
    __shared__ float s_lk[H];

    float lm = lmul[0];
    for (int i = threadIdx.x; i < H; i += blockDim.x) {
        s_issl[i] = rel[i];             // rel[0]: is_slider
        s_slen[i] = rel[H + i];         // rel[1]: slider_lengths
        s_scos[i] = rel[3 * H + i];     // rel[3]: slider cos
        s_ssin[i] = rel[4 * H + i];     // rel[4]: slider sin
        s_lk[i]   = __fmul_rn(lm, rel[5 * H + i]);  // l = lm * note_dist
    }
    __syncthreads();

    const int row = blockIdx.x * blockDim.x + threadIdx.x;
    const int c = blockIdx.y;                          // chunk id (block-uniform)
    const int s = c * CHUNK;
    const bool nfse = (nfse_p[0] != 0);

    const float* rp = mapvars + (size_t)row * (4 * H);

    // ---- recover carry at step s: replay from nearest reset, F4 loads ----
    float px, py;
    if (c == 0) {
        px = start_pos[0];
        py = start_pos[1];
    } else {
        int j = -1;
        for (int t = s - 1; t > 0; --t)
            if (s_lk[t] > 192.0f) { j = t; break; }    // reset: carry-in dead
        int k0;
        if (j < 0) { px = start_pos[0]; py = start_pos[1]; k0 = 0; }
        else       { px = 0.0f;         py = 0.0f;         k0 = j; }
        // aligned 4-step groups; compute guarded by k >= k0 (block-uniform)
        for (int g = k0 & ~3; g < s; g += 4) {
            F4 R[4];
#pragma unroll
            for (int ar = 0; ar < 4; ++ar)
                R[ar] = *(const F4*)(rp + ar * H + g);
#pragma unroll
            for (int jj = 0; jj < 4; ++jj) {
                const int k = g + jj;
                if (k >= k0 && k < s)
                    step_core(R[0].v[jj], R[1].v[jj], R[2].v[jj], R[3].v[jj],
                              s_lk[k], s_issl[k], s_slen[k], s_scos[k], s_ssin[k],
                              nfse, px, py, nullptr);
            }
        }
    }

    // ---- main chunk: full 16-step frames; 64B/lane/array register staging ----
    float* op = out + (size_t)row * (H * 6) + (size_t)s * 6;

    for (int g = 0; g < CHUNK / GRP; ++g) {
        const int k0 = s + g * GRP;

        F4 A[4][GRP / 4];
#pragma unroll
        for (int ar = 0; ar < 4; ++ar)
#pragma unroll
            for (int t = 0; t < GRP / 4; ++t)
                A[ar][t] = *(const F4*)(rp + ar * H + k0 + 4 * t);

#pragma unroll
        for (int t = 0; t < GRP / 4; ++t) {
            float o[24];
#pragma unroll
            for (int j = 0; j < 4; ++j) {
                const int k = k0 + 4 * t + j;
                step_core(A[0][t].v[j], A[1][t].v[j], A[2][t].v[j], A[3][t].v[j],
                          s_lk[k], s_issl[k], s_slen[k], s_scos[k], s_ssin[k],
                          nfse, px, py, o + 6 * j);
            }
            float* ow = op + (g * GRP + 4 * t) * 6;
#pragma unroll
            for (int q = 0; q < 6; ++q) {
                v4f v;
                v.x = o[q * 4 + 0];
                v.y = o[q * 4 + 1];
                v.z = o[q * 4 + 2];
                v.w = o[q * 4 + 3];
                *(v4f*)(ow + 4 * q) = v;   // plain store: L2 write-combines
            }
        }
    }
}

extern "C" void kernel_launch(void* const* d_in, const int* in_sizes, int n_in,
                              void* d_out, int out_size, void* d_ws, size_t ws_size,
                              hipStream_t stream) {
    const float* mapvars = (const float*)d_in[0];
    const float* rel     = (const float*)d_in[1];
    const float* sp      = (const float*)d_in[2];
    const float* lm      = (const float*)d_in[3];
    const int*   nfse    = (const int*)d_in[4];
    float* out = (float*)d_out;

    const int B = in_sizes[0] / (4 * H);   // 32768
    dim3 grid(B / 256, NCH);
    hipLaunchKernelGGL(construct_map_kernel, grid, dim3(256), 0, stream,
                       mapvars, rel, sp, lm, nfse, out);
}

// Round 6
// 270.456 us; speedup vs baseline: 1.6093x; 1.3923x over previous
//
#include <hip/hip_runtime.h>

// KerasCustomMappingLayer: B=32768 rows x H=512 sequential steps, out (B,H,6) f32.
//
// R6 = R3 structure + F4-vectorized replay (from R5), launch_bounds(256,4).
// History of measured lessons baked in:
//  - R1: scalar/16B-granule reads -> 4.6x read overfetch. Use 16-step frames:
//    64B/lane/array contiguous (full-line consumption in registers).
//  - R2: nontemporal stores -> 2.6x write amplification. Plain v4f stores only.
//  - R4: ragged guarded scalar stores -> 2x write amplification. Full frames only.
//  - R5: __launch_bounds__(256,8) forced VGPR=32 -> scratch spills (+110MB
//    write, +110MB fetch). (256,4) gives 48-64 VGPR, zero spill; VGPR<=64
//    still allows 8 waves/SIMD.
//  - Replay from last reset (l[k]>192, k-only, block-uniform) with aligned F4
//    groups; replay-boundary lines are ~50% L2-absorbed (shared with the
//    neighboring chunk's main frames, same XCD since 128%8==0).
// Numerics: exact numpy fp32 graph (contract off, IEEE div/sqrt) so the
// wall-indicator comparisons never flip vs the reference.

#define H 512
#define NCH 16
#define CHUNK 32   // H / NCH
#define GRP 16     // steps per register frame

typedef float v4f __attribute__((ext_vector_type(4)));
struct alignas(16) F4 { float v[4]; };

__device__ __forceinline__ void step_core(
    float m0, float m1, float m2, float m3,
    float lk, float isslf, float slnk, float scosk, float ssink,
    bool nfse, float& px, float& py, float* o /* 6 floats or nullptr */)
{
#pragma clang fp contract(off)
    // wall constants: match numpy's f64-scalar -> f32 cast
    const float WL = (float)(0.05 * 512.0);
    const float WR = (float)(0.95 * 512.0);
    const float WT = (float)(0.05 * 384.0);
    const float WB = (float)(0.95 * 384.0);

    // normalization (cos_list/sin_list): len = sqrt(c*c + s*s); c/len, s/len
    float q0 = __fmul_rn(m0, m0);
    float q2 = __fmul_rn(m2, m2);
    float len1 = __fsqrt_rn(__fadd_rn(q0, q2));
    float ck = __fdiv_rn(m0, len1);
    float sk = __fdiv_rn(m2, len1);
    float q1 = __fmul_rn(m1, m1);
    float q3 = __fmul_rn(m3, m3);
    float len2 = __fsqrt_rn(__fadd_rn(q1, q3));
    float ck2 = __fdiv_rn(m1, len2);
    float sk2 = __fdiv_rn(m3, len2);

    bool rr = lk > 192.0f;                 // l > Y_MAX/2  (the carry reset)
    float half_l = __fmul_rn(lk, 0.5f);
    float wl = __fadd_rn(WL, half_l);
    float wr = __fadd_rn(WR, -half_l);
    float wt = __fadd_rn(WT, half_l);
    float wb = __fadd_rn(WB, -half_l);

    float dx = __fmul_rn(lk, ck);
    float dy = __fmul_rn(lk, sk);
    float adx = fabsf(dx);
    float ady = fabsf(dy);

    // x_delta = |dx|*w_l - |dx|*w_r + dx*w_xm  (exactly one/none region active)
    float xd = (px < wl) ? adx : ((px > wr) ? -adx : (((px > wl) && (px < wr)) ? dx : 0.0f));
    float yd = (py < wt) ? ady : ((py > wb) ? -ady : (((py > wt) && (py < wb)) ? dy : 0.0f));

    float rx = __fadd_rn(256.0f, __fmul_rn(256.0f, m0));  // rerand_x
    float ry = __fadd_rn(192.0f, __fmul_rn(192.0f, m2));  // rerand_y

    float _x = rr ? rx : __fadd_rn(px, xd);
    float _y = rr ? ry : __fadd_rn(py, yd);

    bool issl = isslf != 0.0f;
    float e1 = __fmul_rn(ck2, slnk);
    float e2 = __fmul_rn(sk2, slnk);
    float ex = __fadd_rn(_x, e1);   // _x + ck2*slider_len
    float ey = __fadd_rn(_y, e2);

    if (o) {
        float o0 = __fdiv_rn(_x, 512.0f);
        float o1 = __fdiv_rn(_y, 384.0f);
        o[0] = o0;
        o[1] = o1;
        if (issl) {
            float t1 = __fmul_rn(ck2, scosk);
            float t2 = __fmul_rn(sk2, ssink);
            o[2] = __fadd_rn(t1, -t2);      // _oa
            float t3 = __fmul_rn(ck2, ssink);
            float t4 = __fmul_rn(sk2, scosk);
            o[3] = __fadd_rn(t3, t4);       // _ob
            o[4] = __fdiv_rn(ex, 512.0f);
            o[5] = __fdiv_rn(ey, 384.0f);
        } else {
            o[2] = rr ? ck2 : ck;           // _a = rr*ck2 + nrr*ck
            o[3] = rr ? sk2 : sk;           // _b
            o[4] = o0;
            o[5] = o1;
        }
    }

    if (issl) {
        px = nfse ? ex : _x;
        py = nfse ? ey : _y;
    } else {
        px = _x;
        py = _y;
    }
}

__global__ __launch_bounds__(256, 4)
void construct_map_kernel(const float* __restrict__ mapvars,
                          const float* __restrict__ rel,
                          const float* __restrict__ start_pos,
                          const float* __restrict__ lmul,
                          const int* __restrict__ nfse_p,
                          float* __restrict__ out)
{
    __shared__ float s_issl[H];
    __shared__ float s_slen[H];
    __shared__ float s_scos[H];
    __shared__ float s_ssin[H];
    __shared__ float s_lk[H];

    float lm = lmul[0];
    for (int i = threadIdx.x; i < H; i += blockDim.x) {
        s_issl[i] = rel[i];             // rel[0]: is_slider
        s_slen[i] = rel[H + i];         // rel[1]: slider_lengths
        s_scos[i] = rel[3 * H + i];     // rel[3]: slider cos
        s_ssin[i] = rel[4 * H + i];     // rel[4]: slider sin
        s_lk[i]   = __fmul_rn(lm, rel[5 * H + i]);  // l = lm * note_dist
    }
    __syncthreads();

    const int row = blockIdx.x * blockDim.x + threadIdx.x;
    const int c = blockIdx.y;                          // chunk id (block-uniform)
    const int s = c * CHUNK;
    const bool nfse = (nfse_p[0] != 0);

    const float* rp = mapvars + (size_t)row * (4 * H);

    // ---- recover carry at step s: replay from nearest reset, F4 loads ----
    float px, py;
    if (c == 0) {
        px = start_pos[0];
        py = start_pos[1];
    } else {
        int j = -1;
        for (int t = s - 1; t > 0; --t)
            if (s_lk[t] > 192.0f) { j = t; break; }    // reset: carry-in dead
        int k0;
        if (j < 0) { px = start_pos[0]; py = start_pos[1]; k0 = 0; }
        else       { px = 0.0f;         py = 0.0f;         k0 = j; }
        // aligned 4-step groups; compute guarded by k >= k0 (block-uniform)
        for (int g = k0 & ~3; g < s; g += 4) {
            F4 R[4];
#pragma unroll
            for (int ar = 0; ar < 4; ++ar)
                R[ar] = *(const F4*)(rp + ar * H + g);
#pragma unroll
            for (int jj = 0; jj < 4; ++jj) {
                const int k = g + jj;
                if (k >= k0 && k < s)
                    step_core(R[0].v[jj], R[1].v[jj], R[2].v[jj], R[3].v[jj],
                              s_lk[k], s_issl[k], s_slen[k], s_scos[k], s_ssin[k],
                              nfse, px, py, nullptr);
            }
        }
    }

    // ---- main chunk: full 16-step frames; 64B/lane/array register staging ----
    float* op = out + (size_t)row * (H * 6) + (size_t)s * 6;

    for (int g = 0; g < CHUNK / GRP; ++g) {
        const int k0 = s + g * GRP;

        F4 A[4][GRP / 4];
#pragma unroll
        for (int ar = 0; ar < 4; ++ar)
#pragma unroll
            for (int t = 0; t < GRP / 4; ++t)
                A[ar][t] = *(const F4*)(rp + ar * H + k0 + 4 * t);

#pragma unroll
        for (int t = 0; t < GRP / 4; ++t) {
            float o[24];
#pragma unroll
            for (int j = 0; j < 4; ++j) {
                const int k = k0 + 4 * t + j;
                step_core(A[0][t].v[j], A[1][t].v[j], A[2][t].v[j], A[3][t].v[j],
                          s_lk[k], s_issl[k], s_slen[k], s_scos[k], s_ssin[k],
                          nfse, px, py, o + 6 * j);
            }
            float* ow = op + (g * GRP + 4 * t) * 6;
#pragma unroll
            for (int q = 0; q < 6; ++q) {
                v4f v;
                v.x = o[q * 4 + 0];
                v.y = o[q * 4 + 1];
                v.z = o[q * 4 + 2];
                v.w = o[q * 4 + 3];
                *(v4f*)(ow + 4 * q) = v;   // plain store: L2 write-combines
            }
        }
    }
}

extern "C" void kernel_launch(void* const* d_in, const int* in_sizes, int n_in,
                              void* d_out, int out_size, void* d_ws, size_t ws_size,
                              hipStream_t stream) {
    const float* mapvars = (const float*)d_in[0];
    const float* rel     = (const float*)d_in[1];
    const float* sp      = (const float*)d_in[2];
    const float* lm      = (const float*)d_in[3];
    const int*   nfse    = (const int*)d_in[4];
    float* out = (float*)d_out;

    const int B = in_sizes[0] / (4 * H);   // 32768
    dim3 grid(B / 256, NCH);
    hipLaunchKernelGGL(construct_map_kernel, grid, dim3(256), 0, stream,
                       mapvars, rel, sp, lm, nfse, out);
}